// Round 6
// baseline (432.525 us; speedup 1.0000x reference)
//
#include <hip/hip_runtime.h>
#include <hip/hip_fp16.h>

#define NN 4096
constexpr int TPB = 256;
constexpr int NSTRIP = 4;                    // column strips of 1024
constexpr int CPB = 1024;
constexpr int RPB = 16;                      // rows per block-tile
constexpr int NROWG = NN / RPB;              // 256 row groups
constexpr int NRSLOT = NSTRIP * (TPB / 64);  // 16 row-partial slots
constexpr int NBLK = NSTRIP * NROWG;         // 1024 blocks (exactly 4/CU: co-resident)
constexpr int NSLICE = 64;                   // update slices (64 cols each)

typedef float    f32x4 __attribute__((ext_vector_type(4)));
typedef _Float16 f16x4 __attribute__((ext_vector_type(4)));

__device__ __forceinline__ float sigmoidf_(float x) {
    return 1.0f / (1.0f + __expf(-x));
}

// One 64-column slice of the s-update, done by a late-ranked pass block.
// Fixed reduction order -> bit-deterministic independent of which block runs it.
__device__ __forceinline__ void update_slice(
    int slice, int t, const float* __restrict__ rowpart,
    const float* __restrict__ colpart, const float2* __restrict__ bs, float w,
    float* __restrict__ s1next, float2* __restrict__ out_s, int writeOut) {
    __shared__ float red0[4][64];
    __shared__ float red1[4][64];
    const int col = t & 63;
    const int q = t >> 6;  // 0..3
    const int x = slice * 64 + col;

    float acc1 = 0.f;
#pragma unroll 8
    for (int g = q * 64; g < q * 64 + 64; ++g) acc1 += colpart[(size_t)g * NN + x];
    float acc0 = 0.f;
#pragma unroll
    for (int s = q * 4; s < q * 4 + 4; ++s) acc0 += rowpart[(size_t)s * NN + x];
    red1[q][col] = acc1;
    red0[q][col] = acc0;
    __syncthreads();
    if (q == 0) {
        float m0 = red0[0][col] + red0[1][col] + red0[2][col] + red0[3][col];
        float m1 = red1[0][col] + red1[1][col] + red1[2][col] + red1[3][col];
        float2 b = bs[x];
        float c0 = b.x + w * m0;
        float c1 = b.y + w * m1;
        if (writeOut) out_s[x] = make_float2(c0, c1);
        else s1next[x] = sigmoidf_(c1 - c0);
    }
}

// MODE: 0 = step1 from bf (sigma^1 inline), write fp16 df
//       1 = step1 from bf, no df write (fallback)
//       2 = mid step from fp16 df          3 = mid step from bf (fallback)
//       4 = step5 from bf + out_f epilogue
// After partials, last-64-ranked blocks spin on ctr and run the fused update.
template <int MODE>
__global__ __launch_bounds__(TPB) void pass_kernel(
    const float2* __restrict__ bs, const f32x4* __restrict__ bf,
    f16x4* __restrict__ df, f32x4* __restrict__ of,
    const float* __restrict__ s1c, const float* __restrict__ s1p,
    const float* __restrict__ wptr,
    float* __restrict__ rowpart, float* __restrict__ colpart,
    float* __restrict__ s1store, unsigned* __restrict__ ctr,
    float* __restrict__ s1next, float2* __restrict__ out_s, int writeOut) {
    const int t = threadIdx.x;
    const int bid = blockIdx.x;
    const int strip = bid & (NSTRIP - 1);
    const int rg = bid >> 2;
    const int j0 = strip * CPB + t * 4;
    const int i0 = rg * RPB;
    const float w = wptr[0];

    float s0cv[4], ws0p[4];
#pragma unroll
    for (int k = 0; k < 4; ++k) {
        if (MODE <= 1) {
            float2 v = bs[j0 + k];
            s0cv[k] = 1.0f - sigmoidf_(v.y - v.x);
            ws0p[k] = 0.0f;
        } else {
            s0cv[k] = 1.0f - s1c[j0 + k];
            ws0p[k] = w * (1.0f - s1p[j0 + k]);
        }
    }
    if (MODE <= 1) {  // 16 blocks persist sigma^1 for step 2's prev
        if (bid < NN / TPB) {
            int x = bid * TPB + t;
            float2 v = bs[x];
            s1store[x] = sigmoidf_(v.y - v.x);
        }
    }
    float colacc[4] = {0.f, 0.f, 0.f, 0.f};
    for (int r = 0; r < RPB; ++r) {
        const int i = i0 + r;
        float s1ci, s1pi;
        if (MODE <= 1) {
            float2 v = bs[i];
            s1ci = sigmoidf_(v.y - v.x);
            s1pi = 0.0f;
        } else {
            s1ci = s1c[i];
            s1pi = s1p[i];
        }
        float dd[4];
        if (MODE == 2) {
            f16x4 h = reinterpret_cast<const f16x4*>(df)[((size_t)i * NN + j0) >> 2];
            dd[0] = (float)h.x; dd[1] = (float)h.y;
            dd[2] = (float)h.z; dd[3] = (float)h.w;
        } else {
            const size_t u = ((size_t)i * NN + j0) >> 1;
            f32x4 a = bf[u];
            f32x4 b = bf[u + 1];
            dd[0] = a.y - a.x; dd[1] = a.w - a.z;
            dd[2] = b.y - b.x; dd[3] = b.w - b.z;
            if (MODE == 0) {
                f16x4 h;
                h.x = (_Float16)dd[0]; h.y = (_Float16)dd[1];
                h.z = (_Float16)dd[2]; h.w = (_Float16)dd[3];
                df[((size_t)i * NN + j0) >> 2] = h;
            }
            if (MODE == 4) {
                const float wi = w * s1ci;
                f32x4 oa = {a.x + wi * s0cv[0], a.y, a.z + wi * s0cv[1], a.w};
                f32x4 ob = {b.x + wi * s0cv[2], b.y, b.z + wi * s0cv[3], b.w};
                __builtin_nontemporal_store(oa, of + u);
                __builtin_nontemporal_store(ob, of + u + 1);
            }
        }
        float rowp = 0.f;
#pragma unroll
        for (int k = 0; k < 4; ++k) {
            float f1 = sigmoidf_(dd[k] - s1pi * ws0p[k]);
            colacc[k] += s1ci * f1;
            rowp += f1 * s0cv[k];
        }
#pragma unroll
        for (int off = 32; off > 0; off >>= 1) rowp += __shfl_down(rowp, off);
        if ((t & 63) == 0)
            rowpart[(size_t)(strip * (TPB / 64) + (t >> 6)) * NN + i] = rowp;
    }
    *reinterpret_cast<f32x4*>(colpart + (size_t)rg * NN + j0) =
        f32x4{colacc[0], colacc[1], colacc[2], colacc[3]};

    // ---- fused update: last-64-ranked blocks reduce the partials ----
    __shared__ unsigned s_rank;
    __syncthreads();  // all threads' partial stores issued
    if (t == 0) {
        __threadfence();  // release: partials visible device-wide before count
        s_rank = atomicAdd(ctr, 1u);
    }
    __syncthreads();
    const unsigned rank = s_rank;
    if (rank >= (unsigned)(NBLK - NSLICE)) {
        if (t == 0) {
            while (__hip_atomic_load(ctr, __ATOMIC_ACQUIRE,
                                     __HIP_MEMORY_SCOPE_AGENT) < (unsigned)NBLK)
                __builtin_amdgcn_s_sleep(8);
        }
        __syncthreads();
        __threadfence();  // acquire: see all blocks' partials
        update_slice((int)(rank - (NBLK - NSLICE)), t, rowpart, colpart, bs, w,
                     s1next, out_s, writeOut);
    }
}

extern "C" void kernel_launch(void* const* d_in, const int* in_sizes, int n_in,
                              void* d_out, int out_size, void* d_ws,
                              size_t ws_size, hipStream_t stream) {
    const float2* bs = (const float2*)d_in[0];   // (N,2)
    const f32x4* bf = (const f32x4*)d_in[1];     // (N,N,2)
    const float* wptr = (const float*)d_in[2];   // (1,)
    float2* out_s = (float2*)d_out;
    f32x4* out_f = (f32x4*)((float*)d_out + 2 * NN);

    char* ws = (char*)d_ws;
    size_t off = 0;
    auto alloc = [&](size_t bytes) {
        void* p = ws + off;
        off = (off + bytes + 255) & ~(size_t)255;
        return p;
    };
    unsigned* ctrs = (unsigned*)alloc(8 * sizeof(unsigned));  // 5 used
    float* sa = (float*)alloc((size_t)NN * 4);
    float* sb = (float*)alloc((size_t)NN * 4);
    float* sc = (float*)alloc((size_t)NN * 4);
    float* rowpart = (float*)alloc((size_t)NRSLOT * NN * 4);
    float* colpart = (float*)alloc((size_t)NROWG * NN * 4);
    f16x4* df = (f16x4*)(ws + off);
    const bool use_df = (ws_size >= off + (size_t)NN * NN * 2);

    // zero the arrival counters (survives the 0xAA ws poison; graph-capturable)
    hipMemsetAsync(ctrs, 0, 8 * sizeof(unsigned), stream);

    const dim3 gP(NBLK), bP(TPB);

    if (use_df) {
        // step 1: sigma^1 -> sa, df written, fused update -> sb = sigma^2
        pass_kernel<0><<<gP, bP, 0, stream>>>(bs, bf, df, nullptr, nullptr, nullptr,
                                              wptr, rowpart, colpart, sa, ctrs + 0,
                                              sb, nullptr, 0);
        // step 2: cur=sigma^2, prev=sigma^1 -> sc = sigma^3
        pass_kernel<2><<<gP, bP, 0, stream>>>(bs, bf, df, nullptr, sb, sa, wptr,
                                              rowpart, colpart, nullptr, ctrs + 1,
                                              sc, nullptr, 0);
        // step 3: cur=sigma^3, prev=sigma^2 -> sa = sigma^4
        pass_kernel<2><<<gP, bP, 0, stream>>>(bs, bf, df, nullptr, sc, sb, wptr,
                                              rowpart, colpart, nullptr, ctrs + 2,
                                              sa, nullptr, 0);
        // step 4: cur=sigma^4, prev=sigma^3 -> sb = sigma^5
        pass_kernel<2><<<gP, bP, 0, stream>>>(bs, bf, df, nullptr, sa, sc, wptr,
                                              rowpart, colpart, nullptr, ctrs + 3,
                                              sb, nullptr, 0);
        // step 5: cur=sigma^5(sb), prev=sigma^4(sa); out_f epilogue; update -> out_s
        pass_kernel<4><<<gP, bP, 0, stream>>>(bs, bf, df, out_f, sb, sa, wptr,
                                              rowpart, colpart, nullptr, ctrs + 4,
                                              nullptr, out_s, 1);
    } else {
        pass_kernel<1><<<gP, bP, 0, stream>>>(bs, bf, df, nullptr, nullptr, nullptr,
                                              wptr, rowpart, colpart, sa, ctrs + 0,
                                              sb, nullptr, 0);
        pass_kernel<3><<<gP, bP, 0, stream>>>(bs, bf, df, nullptr, sb, sa, wptr,
                                              rowpart, colpart, nullptr, ctrs + 1,
                                              sc, nullptr, 0);
        pass_kernel<3><<<gP, bP, 0, stream>>>(bs, bf, df, nullptr, sc, sb, wptr,
                                              rowpart, colpart, nullptr, ctrs + 2,
                                              sa, nullptr, 0);
        pass_kernel<3><<<gP, bP, 0, stream>>>(bs, bf, df, nullptr, sa, sc, wptr,
                                              rowpart, colpart, nullptr, ctrs + 3,
                                              sb, nullptr, 0);
        pass_kernel<4><<<gP, bP, 0, stream>>>(bs, bf, df, out_f, sb, sa, wptr,
                                              rowpart, colpart, nullptr, ctrs + 4,
                                              nullptr, out_s, 1);
    }
}

// Round 7
// 250.249 us; speedup vs baseline: 1.7284x; 1.7284x over previous
//
#include <hip/hip_runtime.h>
#include <hip/hip_fp16.h>

#define NN 4096
constexpr int TPB = 256;
constexpr int NSTRIP = 4;                 // column strips of 1024
constexpr int CPB = 1024;
constexpr int RPB = 16;                   // rows per block-tile
constexpr int NROWG = NN / RPB;           // 256 row groups
constexpr int NBLK = NSTRIP * NROWG;      // 1024 blocks

typedef float    f32x4 __attribute__((ext_vector_type(4)));
typedef _Float16 f16x4 __attribute__((ext_vector_type(4)));
typedef unsigned long long u64;

constexpr double SCALE = 1099511627776.0;         // 2^40
constexpr double INV_SCALE = 1.0 / 1099511627776.0;

__device__ __forceinline__ float sigmoidf_(float x) {
    return 1.0f / (1.0f + __expf(-x));
}
__device__ __forceinline__ float fromI(u64 v) {
    return (float)((double)v * INV_SCALE);
}

// sigma^cur, sigma^prev at index idx.
// STEPK==1: cur from bs only, prev:=0 (kills the w term exactly as w*0).
// STEPK==2: cur from sums C, prev from bs. STEPK>=3: cur from C, prev from P.
template <int STEPK>
__device__ __forceinline__ void sig_pair(
    int idx, const float2* __restrict__ bs,
    const u64* __restrict__ rsC, const u64* __restrict__ csC,
    const u64* __restrict__ rsP, const u64* __restrict__ csP,
    float w, float& sc, float& sp) {
    float2 b = bs[idx];
    if (STEPK == 1) { sc = sigmoidf_(b.y - b.x); sp = 0.f; return; }
    float c0 = b.x + w * fromI(rsC[idx]);
    float c1 = b.y + w * fromI(csC[idx]);
    sc = sigmoidf_(c1 - c0);
    if (STEPK == 2) {
        sp = sigmoidf_(b.y - b.x);
    } else {
        sp = sigmoidf_((b.y + w * fromI(csP[idx])) - (b.x + w * fromI(rsP[idx])));
    }
}

// SRC: 0 = read base_f (f32 pairs), 1 = read fp16 df.
// WRITE_DF: step-1 writes df. EPI: step-5 fused out_f epilogue (requires SRC=0).
// Message sums accumulate into rsO/csO as fixed-point u64 atomics
// (integer adds commute -> bit-deterministic).
template <int STEPK, int SRC, int WRITE_DF, int EPI>
__global__ __launch_bounds__(TPB) void pass_kernel(
    const float2* __restrict__ bs, const f32x4* __restrict__ bf,
    f16x4* __restrict__ df, f32x4* __restrict__ of,
    const u64* __restrict__ rsC, const u64* __restrict__ csC,
    const u64* __restrict__ rsP, const u64* __restrict__ csP,
    u64* __restrict__ rsO, u64* __restrict__ csO,
    const float* __restrict__ wptr) {
    const int t = threadIdx.x;
    const int bid = blockIdx.x;
    const int strip = bid & (NSTRIP - 1);
    const int rg = bid >> 2;
    const int j0 = strip * CPB + t * 4;
    const int i0 = rg * RPB;
    const float w = wptr[0];

    float s0cv[4], ws0p[4];
#pragma unroll
    for (int k = 0; k < 4; ++k) {
        float sc, sp;
        sig_pair<STEPK>(j0 + k, bs, rsC, csC, rsP, csP, w, sc, sp);
        s0cv[k] = 1.0f - sc;
        ws0p[k] = w * (1.0f - sp);
    }
    float colacc[4] = {0.f, 0.f, 0.f, 0.f};

#pragma unroll 4
    for (int r = 0; r < RPB; ++r) {
        const int i = i0 + r;
        float s1ci, s1pi;
        sig_pair<STEPK>(i, bs, rsC, csC, rsP, csP, w, s1ci, s1pi);  // uniform -> scalar loads
        float dd[4];
        if (SRC == 1) {
            f16x4 h = df[((size_t)i * NN + j0) >> 2];
            dd[0] = (float)h.x; dd[1] = (float)h.y;
            dd[2] = (float)h.z; dd[3] = (float)h.w;
        } else {
            const size_t u = ((size_t)i * NN + j0) >> 1;
            f32x4 a = bf[u];
            f32x4 b2 = bf[u + 1];
            dd[0] = a.y - a.x; dd[1] = a.w - a.z;
            dd[2] = b2.y - b2.x; dd[3] = b2.w - b2.z;
            if (WRITE_DF) {
                f16x4 h;
                h.x = (_Float16)dd[0]; h.y = (_Float16)dd[1];
                h.z = (_Float16)dd[2]; h.w = (_Float16)dd[3];
                df[((size_t)i * NN + j0) >> 2] = h;
            }
            if (EPI) {
                const float wi = w * s1ci;  // w * sigma^5[i]
                f32x4 oa = {a.x + wi * s0cv[0], a.y, a.z + wi * s0cv[1], a.w};
                f32x4 ob = {b2.x + wi * s0cv[2], b2.y, b2.z + wi * s0cv[3], b2.w};
                __builtin_nontemporal_store(oa, of + u);
                __builtin_nontemporal_store(ob, of + u + 1);
            }
        }
        float rowp = 0.f;
#pragma unroll
        for (int k = 0; k < 4; ++k) {
            float f1 = sigmoidf_(dd[k] - s1pi * ws0p[k]);
            colacc[k] += s1ci * f1;
            rowp += f1 * s0cv[k];
        }
#pragma unroll
        for (int off = 32; off > 0; off >>= 1) rowp += __shfl_down(rowp, off);
        if ((t & 63) == 0)
            atomicAdd(&rsO[i], (u64)((double)rowp * SCALE));  // rowp < 256 -> <2^48
    }
#pragma unroll
    for (int k = 0; k < 4; ++k)
        atomicAdd(&csO[j0 + k], (u64)((double)colacc[k] * SCALE));  // <16 -> <2^44
}

// out_s from step-5 sums (16 blocks x 256).
__global__ __launch_bounds__(256) void outs_kernel(
    const float2* __restrict__ bs, const u64* __restrict__ rs5,
    const u64* __restrict__ cs5, const float* __restrict__ wptr,
    float2* __restrict__ out_s) {
    int x = blockIdx.x * 256 + threadIdx.x;
    float w = wptr[0];
    float2 b = bs[x];
    out_s[x] = make_float2(b.x + w * fromI(rs5[x]), b.y + w * fromI(cs5[x]));
}

extern "C" void kernel_launch(void* const* d_in, const int* in_sizes, int n_in,
                              void* d_out, int out_size, void* d_ws,
                              size_t ws_size, hipStream_t stream) {
    const float2* bs = (const float2*)d_in[0];   // (N,2)
    const f32x4* bf = (const f32x4*)d_in[1];     // (N,N,2)
    const float* wptr = (const float*)d_in[2];   // (1,)
    float2* out_s = (float2*)d_out;
    f32x4* out_f = (f32x4*)((float*)d_out + 2 * NN);

    char* ws = (char*)d_ws;
    size_t off = 0;
    auto alloc = [&](size_t bytes) {
        void* p = ws + off;
        off = (off + bytes + 255) & ~(size_t)255;
        return p;
    };
    // 5 steps x (rowsum, colsum) x NN u64
    u64* S = (u64*)alloc((size_t)5 * 2 * NN * sizeof(u64));  // 320 KB
    f16x4* df = (f16x4*)(ws + off);
    const bool use_df = (ws_size >= off + (size_t)NN * NN * 2);

    auto rs = [&](int k) { return S + (size_t)(k - 1) * 2 * NN; };
    auto cs = [&](int k) { return S + (size_t)(k - 1) * 2 * NN + NN; };

    hipMemsetAsync(S, 0, (size_t)5 * 2 * NN * sizeof(u64), stream);

    const dim3 gP(NBLK), bP(TPB);
    const u64* nil = nullptr;

    if (use_df) {
        // step 1: read bf, write df; sums1
        pass_kernel<1, 0, 1, 0><<<gP, bP, 0, stream>>>(
            bs, bf, df, nullptr, nil, nil, nil, nil, rs(1), cs(1), wptr);
        // step 2: cur=sigma^2 (sums1), prev=sigma^1 (bs); read df; sums2
        pass_kernel<2, 1, 0, 0><<<gP, bP, 0, stream>>>(
            bs, bf, df, nullptr, rs(1), cs(1), nil, nil, rs(2), cs(2), wptr);
        // step 3: cur=sums2, prev=sums1; sums3
        pass_kernel<3, 1, 0, 0><<<gP, bP, 0, stream>>>(
            bs, bf, df, nullptr, rs(2), cs(2), rs(1), cs(1), rs(3), cs(3), wptr);
        // step 4: cur=sums3, prev=sums2; sums4
        pass_kernel<3, 1, 0, 0><<<gP, bP, 0, stream>>>(
            bs, bf, df, nullptr, rs(3), cs(3), rs(2), cs(2), rs(4), cs(4), wptr);
        // step 5: cur=sigma^5 (sums4), prev=sigma^4 (sums3); read bf, out_f epi; sums5
        pass_kernel<3, 0, 0, 1><<<gP, bP, 0, stream>>>(
            bs, bf, df, out_f, rs(4), cs(4), rs(3), cs(3), rs(5), cs(5), wptr);
    } else {
        pass_kernel<1, 0, 0, 0><<<gP, bP, 0, stream>>>(
            bs, bf, df, nullptr, nil, nil, nil, nil, rs(1), cs(1), wptr);
        pass_kernel<2, 0, 0, 0><<<gP, bP, 0, stream>>>(
            bs, bf, df, nullptr, rs(1), cs(1), nil, nil, rs(2), cs(2), wptr);
        pass_kernel<3, 0, 0, 0><<<gP, bP, 0, stream>>>(
            bs, bf, df, nullptr, rs(2), cs(2), rs(1), cs(1), rs(3), cs(3), wptr);
        pass_kernel<3, 0, 0, 0><<<gP, bP, 0, stream>>>(
            bs, bf, df, nullptr, rs(3), cs(3), rs(2), cs(2), rs(4), cs(4), wptr);
        pass_kernel<3, 0, 0, 1><<<gP, bP, 0, stream>>>(
            bs, bf, df, out_f, rs(4), cs(4), rs(3), cs(3), rs(5), cs(5), wptr);
    }
    outs_kernel<<<NN / 256, 256, 0, stream>>>(bs, rs(5), cs(5), wptr, out_s);
}

// Round 8
// 150.763 us; speedup vs baseline: 2.8689x; 1.6599x over previous
//
#include <hip/hip_runtime.h>
#include <hip/hip_fp16.h>

#define NN 4096
constexpr int TPB = 256;
constexpr int NSTRIP = 2;                    // column strips of 2048
constexpr int CPB = 2048;                    // 256 thr x 8 cols
constexpr int RPB = 8;                       // rows per block-tile
constexpr int NROWG = NN / RPB;              // 512 row groups
constexpr int NRSLOT = NSTRIP * (TPB / 64);  // 8 row-partial slots
constexpr int NBLK = NSTRIP * NROWG;         // 1024 blocks (4/CU co-resident)

typedef float    f32x4 __attribute__((ext_vector_type(4)));
typedef _Float16 f16x8 __attribute__((ext_vector_type(8)));

__device__ __forceinline__ float sigmoidf_(float x) {
    return 1.0f / (1.0f + __expf(-x));
}

// MODE: 0 = step1 from bf (sigma^1 inline), write fp16 df
//       1 = step1 from bf, no df write (fallback)
//       2 = mid step from fp16 df          3 = mid step from bf (fallback)
//       4 = step5 from bf + out_f epilogue (plain stores)
template <int MODE>
__global__ __launch_bounds__(TPB) void pass_kernel(
    const float2* __restrict__ bs, const f32x4* __restrict__ bf,
    f16x8* __restrict__ df, f32x4* __restrict__ of,
    const float* __restrict__ s1c, const float* __restrict__ s1p,
    const float* __restrict__ wptr,
    float* __restrict__ rowpart, float* __restrict__ colpart,
    float* __restrict__ s1store) {
    const int t = threadIdx.x;
    const int bid = blockIdx.x;
    const int strip = bid & (NSTRIP - 1);
    const int rg = bid >> 1;
    const int j0 = strip * CPB + t * 8;
    const int i0 = rg * RPB;
    const float w = wptr[0];

    float s0cv[8], ws0p[8];
#pragma unroll
    for (int k = 0; k < 8; ++k) {
        if (MODE <= 1) {
            float2 v = bs[j0 + k];
            s0cv[k] = 1.0f - sigmoidf_(v.y - v.x);
            ws0p[k] = 0.0f;
        } else {
            s0cv[k] = 1.0f - s1c[j0 + k];
            ws0p[k] = w * (1.0f - s1p[j0 + k]);
        }
    }
    if (MODE <= 1) {  // 16 blocks persist sigma^1 for step 2's prev
        if (bid < NN / TPB) {
            int x = bid * TPB + t;
            float2 v = bs[x];
            s1store[x] = sigmoidf_(v.y - v.x);
        }
    }
    float colacc[8] = {0.f, 0.f, 0.f, 0.f, 0.f, 0.f, 0.f, 0.f};

#pragma unroll 2
    for (int r = 0; r < RPB; ++r) {
        const int i = i0 + r;
        float s1ci, s1pi;
        if (MODE <= 1) {
            float2 v = bs[i];
            s1ci = sigmoidf_(v.y - v.x);
            s1pi = 0.0f;
        } else {
            s1ci = s1c[i];
            s1pi = s1p[i];
        }
        float dd[8];
        if (MODE == 2) {
            f16x8 h = df[((size_t)i * NN + j0) >> 3];
#pragma unroll
            for (int k = 0; k < 8; ++k) dd[k] = (float)h[k];
        } else {
            const size_t u = ((size_t)i * NN + j0) >> 1;  // f32x4 index
            f32x4 v0 = bf[u], v1 = bf[u + 1], v2 = bf[u + 2], v3 = bf[u + 3];
            dd[0] = v0.y - v0.x; dd[1] = v0.w - v0.z;
            dd[2] = v1.y - v1.x; dd[3] = v1.w - v1.z;
            dd[4] = v2.y - v2.x; dd[5] = v2.w - v2.z;
            dd[6] = v3.y - v3.x; dd[7] = v3.w - v3.z;
            if (MODE == 0) {
                f16x8 h;
#pragma unroll
                for (int k = 0; k < 8; ++k) h[k] = (_Float16)dd[k];
                df[((size_t)i * NN + j0) >> 3] = h;
            }
            if (MODE == 4) {
                const float wi = w * s1ci;  // w * sigma^5[i]
                of[u]     = f32x4{v0.x + wi * s0cv[0], v0.y, v0.z + wi * s0cv[1], v0.w};
                of[u + 1] = f32x4{v1.x + wi * s0cv[2], v1.y, v1.z + wi * s0cv[3], v1.w};
                of[u + 2] = f32x4{v2.x + wi * s0cv[4], v2.y, v2.z + wi * s0cv[5], v2.w};
                of[u + 3] = f32x4{v3.x + wi * s0cv[6], v3.y, v3.z + wi * s0cv[7], v3.w};
            }
        }
        float rowp = 0.f;
#pragma unroll
        for (int k = 0; k < 8; ++k) {
            float f1 = sigmoidf_(dd[k] - s1pi * ws0p[k]);
            colacc[k] += s1ci * f1;
            rowp += f1 * s0cv[k];
        }
#pragma unroll
        for (int off = 32; off > 0; off >>= 1) rowp += __shfl_down(rowp, off);
        if ((t & 63) == 0)
            rowpart[(size_t)(strip * (TPB / 64) + (t >> 6)) * NN + i] = rowp;
    }
    float* cp = colpart + (size_t)rg * NN + j0;
    *reinterpret_cast<f32x4*>(cp) = f32x4{colacc[0], colacc[1], colacc[2], colacc[3]};
    *reinterpret_cast<f32x4*>(cp + 4) = f32x4{colacc[4], colacc[5], colacc[6], colacc[7]};
}

// 64 blocks x 1024 threads: 16 slices x 64 columns. Slice sl sums colpart
// groups [sl*32, sl*32+32); slices 0..7 also pick up one rowpart slot.
// Fixed order -> deterministic.
__global__ __launch_bounds__(1024) void update_kernel(
    const float* __restrict__ rowpart, const float* __restrict__ colpart,
    const float2* __restrict__ bs, const float* __restrict__ wptr,
    float* __restrict__ s1next, float2* __restrict__ out_s, int writeOut) {
    __shared__ float red0[16][64];
    __shared__ float red1[16][64];
    const int col = threadIdx.x & 63;
    const int sl = threadIdx.x >> 6;  // 0..15
    const int x = blockIdx.x * 64 + col;

    float acc1 = 0.f;
    const int g0 = sl * (NROWG / 16);
#pragma unroll 8
    for (int g = g0; g < g0 + NROWG / 16; ++g) acc1 += colpart[(size_t)g * NN + x];
    red1[sl][col] = acc1;
    red0[sl][col] = (sl < NRSLOT) ? rowpart[(size_t)sl * NN + x] : 0.f;
    __syncthreads();
    if (sl == 0) {
        float m0 = 0.f, m1 = 0.f;
#pragma unroll
        for (int s = 0; s < 16; ++s) {
            m0 += red0[s][col];
            m1 += red1[s][col];
        }
        float w = wptr[0];
        float2 b = bs[x];
        float c0 = b.x + w * m0;
        float c1 = b.y + w * m1;
        if (writeOut) out_s[x] = make_float2(c0, c1);
        else s1next[x] = sigmoidf_(c1 - c0);
    }
}

extern "C" void kernel_launch(void* const* d_in, const int* in_sizes, int n_in,
                              void* d_out, int out_size, void* d_ws,
                              size_t ws_size, hipStream_t stream) {
    const float2* bs = (const float2*)d_in[0];   // (N,2)
    const f32x4* bf = (const f32x4*)d_in[1];     // (N,N,2)
    const float* wptr = (const float*)d_in[2];   // (1,)
    float2* out_s = (float2*)d_out;
    f32x4* out_f = (f32x4*)((float*)d_out + 2 * NN);

    char* ws = (char*)d_ws;
    size_t off = 0;
    auto alloc = [&](size_t bytes) {
        void* p = ws + off;
        off = (off + bytes + 255) & ~(size_t)255;
        return p;
    };
    float* sa = (float*)alloc((size_t)NN * 4);
    float* sb = (float*)alloc((size_t)NN * 4);
    float* sc = (float*)alloc((size_t)NN * 4);
    float* rowpart = (float*)alloc((size_t)NRSLOT * NN * 4);
    float* colpart = (float*)alloc((size_t)NROWG * NN * 4);
    f16x8* df = (f16x8*)(ws + off);
    const bool use_df = (ws_size >= off + (size_t)NN * NN * 2);

    const dim3 gP(NBLK), bP(TPB);
    const dim3 gU(NN / 64), bU(1024);

    // step 1: sigma^1 inline (sa), df written; update -> sb = sigma^2
    if (use_df)
        pass_kernel<0><<<gP, bP, 0, stream>>>(bs, bf, df, nullptr, nullptr,
                                              nullptr, wptr, rowpart, colpart, sa);
    else
        pass_kernel<1><<<gP, bP, 0, stream>>>(bs, bf, df, nullptr, nullptr,
                                              nullptr, wptr, rowpart, colpart, sa);
    update_kernel<<<gU, bU, 0, stream>>>(rowpart, colpart, bs, wptr, sb, nullptr, 0);

    if (use_df) {
        // step 2: cur=sigma^2, prev=sigma^1 -> sc = sigma^3
        pass_kernel<2><<<gP, bP, 0, stream>>>(bs, bf, df, nullptr, sb, sa, wptr,
                                              rowpart, colpart, nullptr);
        update_kernel<<<gU, bU, 0, stream>>>(rowpart, colpart, bs, wptr, sc, nullptr, 0);
        // step 3: cur=sigma^3, prev=sigma^2 -> sa = sigma^4
        pass_kernel<2><<<gP, bP, 0, stream>>>(bs, bf, df, nullptr, sc, sb, wptr,
                                              rowpart, colpart, nullptr);
        update_kernel<<<gU, bU, 0, stream>>>(rowpart, colpart, bs, wptr, sa, nullptr, 0);
        // step 4: cur=sigma^4, prev=sigma^3 -> sb = sigma^5
        pass_kernel<2><<<gP, bP, 0, stream>>>(bs, bf, df, nullptr, sa, sc, wptr,
                                              rowpart, colpart, nullptr);
        update_kernel<<<gU, bU, 0, stream>>>(rowpart, colpart, bs, wptr, sb, nullptr, 0);
    } else {
        pass_kernel<3><<<gP, bP, 0, stream>>>(bs, bf, df, nullptr, sb, sa, wptr,
                                              rowpart, colpart, nullptr);
        update_kernel<<<gU, bU, 0, stream>>>(rowpart, colpart, bs, wptr, sc, nullptr, 0);
        pass_kernel<3><<<gP, bP, 0, stream>>>(bs, bf, df, nullptr, sc, sb, wptr,
                                              rowpart, colpart, nullptr);
        update_kernel<<<gU, bU, 0, stream>>>(rowpart, colpart, bs, wptr, sa, nullptr, 0);
        pass_kernel<3><<<gP, bP, 0, stream>>>(bs, bf, df, nullptr, sa, sc, wptr,
                                              rowpart, colpart, nullptr);
        update_kernel<<<gU, bU, 0, stream>>>(rowpart, colpart, bs, wptr, sb, nullptr, 0);
    }
    // step 5: cur=sigma^5 (sb), prev=sigma^4 (sa); fused out_f epilogue
    pass_kernel<4><<<gP, bP, 0, stream>>>(bs, bf, df, out_f, sb, sa, wptr,
                                          rowpart, colpart, nullptr);
    update_kernel<<<gU, bU, 0, stream>>>(rowpart, colpart, bs, wptr, nullptr, out_s, 1);
}